// Round 7
// baseline (927.786 us; speedup 1.0000x reference)
//
#include <hip/hip_runtime.h>
#include <hip/hip_bf16.h>
#include <hip/hip_fp16.h>

#define SEQ 8192
#define DM  1024   // d_in == d_out == 1024

typedef __attribute__((ext_vector_type(8)))  short    bf16x8;
typedef __attribute__((ext_vector_type(8)))  _Float16 f16x8;
typedef __attribute__((ext_vector_type(4)))  float    f32x4;
typedef __attribute__((ext_vector_type(16))) float    f32x16;

union H8 { _Float16 h[8]; int4 v; };

__device__ __forceinline__ unsigned short f2bf(float f) {
    union { float f; unsigned u; } x; x.f = f;
    unsigned r = x.u + 0x7fffu + ((x.u >> 16) & 1u);
    return (unsigned short)(r >> 16);
}
__device__ __forceinline__ float bf2f(unsigned short h) {
    union { unsigned u; float f; } x; x.u = ((unsigned)h) << 16;
    return x.f;
}

// async global->LDS, 16B per lane; lds dest wave-uniform base (HW adds lane*16)
__device__ __forceinline__ void gld16(const unsigned short* g, unsigned short* l) {
    __builtin_amdgcn_global_load_lds(
        (const __attribute__((address_space(1))) void*)g,
        (__attribute__((address_space(3))) void*)l, 16, 0, 0);
}

// ---------------- split x (fp32 -> bf16 hi/lo) ----------------
__global__ __launch_bounds__(256) void split_x_kernel(const float* __restrict__ x,
    unsigned short* __restrict__ xhi, unsigned short* __restrict__ xlo, int n)
{
    int base = (blockIdx.x * 256 + threadIdx.x) * 4;
    if (base >= n) return;
    float4 v = *(const float4*)(x + base);
    float f[4] = {v.x, v.y, v.z, v.w};
    unsigned short h[4], l[4];
#pragma unroll
    for (int j = 0; j < 4; j++) { h[j] = f2bf(f[j]); l[j] = f2bf(f[j] - bf2f(h[j])); }
    ushort4 hv = {h[0], h[1], h[2], h[3]};
    ushort4 lv = {l[0], l[1], l[2], l[3]};
    *(ushort4*)(xhi + base) = hv;
    *(ushort4*)(xlo + base) = lv;
}

// --- transpose + split all 3 W [1024k x 1024n] -> Wt hi/lo [n][k]; blockIdx.z picks W ---
__global__ __launch_bounds__(256) void wsplit3_kernel(
    const float* W0, const float* W1, const float* W2,
    unsigned short* H0, unsigned short* L0,
    unsigned short* H1, unsigned short* L1,
    unsigned short* H2, unsigned short* L2)
{
    const float* W = (blockIdx.z == 0) ? W0 : (blockIdx.z == 1) ? W1 : W2;
    unsigned short* Wthi = (blockIdx.z == 0) ? H0 : (blockIdx.z == 1) ? H1 : H2;
    unsigned short* Wtlo = (blockIdx.z == 0) ? L0 : (blockIdx.z == 1) ? L1 : L2;

    __shared__ float tile[64][65];
    int bn = blockIdx.x * 64;
    int bk = blockIdx.y * 64;
    int t = threadIdx.x;
#pragma unroll
    for (int p = 0; p < 4; p++) {
        int r = p * 16 + (t >> 4);
        int c = (t & 15) * 4;
        float4 v = *(const float4*)(W + (size_t)(bk + r) * DM + bn + c);
        tile[r][c] = v.x; tile[r][c+1] = v.y; tile[r][c+2] = v.z; tile[r][c+3] = v.w;
    }
    __syncthreads();
#pragma unroll
    for (int p = 0; p < 2; p++) {
        int task = p * 256 + t;
        int rn = task >> 3;
        int kc = (task & 7) * 8;
        union { unsigned short u[8]; int4 v; } hh, ll;
#pragma unroll
        for (int j = 0; j < 8; j++) {
            float f = tile[kc + j][rn];
            hh.u[j] = f2bf(f);
            ll.u[j] = f2bf(f - bf2f(hh.u[j]));
        }
        size_t o = (size_t)(bn + rn) * DM + bk + kc;
        *(int4*)(Wthi + o) = hh.v;
        *(int4*)(Wtlo + o) = ll.v;
    }
}

// ============ 128x128-tile GEMM, 256 threads (4 waves, 64x64 each), BK=32 ============
// MODE 0: split bf16 -> split bf16 out; blockIdx.z picks (B,out) pair (Q/K projections)
// MODE 1: plain bf16 -> f16 out row-major (V projection), KD=1024
// MODE 3: plain f16 -> f32 out (PV), KD=8192; grid x=row-tile for XCD L2 sharing
template<int MODE, int KD>
__global__ __launch_bounds__(256) void gemm128(
    const unsigned short* A,   const unsigned short* Alo,
    const unsigned short* B_,  const unsigned short* Blo_,
    const unsigned short* B2,  const unsigned short* B2lo,
    unsigned short* Chi_, unsigned short* Clo_,
    unsigned short* Chi2, unsigned short* Clo2,
    _Float16* Cf16, float* Cf32)
{
    constexpr bool SPLIT = (MODE == 0);
    __shared__ alignas(16) unsigned short sAhi[128 * 32];
    __shared__ alignas(16) unsigned short sBhi[128 * 32];
    __shared__ alignas(16) unsigned short sAlo[SPLIT ? 128 * 32 : 16];
    __shared__ alignas(16) unsigned short sBlo[SPLIT ? 128 * 32 : 16];

    const unsigned short* B   = B_;
    const unsigned short* Blo = Blo_;
    unsigned short* Chi = Chi_;
    unsigned short* Clo = Clo_;
    if (MODE == 0 && blockIdx.z == 1) { B = B2; Blo = B2lo; Chi = Chi2; Clo = Clo2; }

    const int m0 = blockIdx.x * 128;
    const int n0 = blockIdx.y * 128;
    const int t = threadIdx.x;
    const int wave = t >> 6, lane = t & 63;
    const int wr = wave >> 1, wc = wave & 1;    // wave quadrant (64x64)
    const int i16 = lane & 15, quad = lane >> 4;

    // staging: wave stages rows wave*32 .. wave*32+31 (two 16-row chunks)
    const int rs = wave * 32 + (lane >> 2);
    const int cs = (lane & 3) * 8;
    const size_t aoff = (size_t)(m0 + rs) * KD + cs;
    const size_t boff = (size_t)(n0 + rs) * KD + cs;
    const int ldsb = wave * 1024;   // element offset of this wave's staging region

    f32x4 acc[4][4] = {};

    for (int k = 0; k < KD; k += 32) {
        __syncthreads();
        gld16(A + aoff + k,            sAhi + ldsb);
        gld16(A + aoff + 16 * KD + k,  sAhi + ldsb + 512);
        gld16(B + boff + k,            sBhi + ldsb);
        gld16(B + boff + 16 * KD + k,  sBhi + ldsb + 512);
        if constexpr (SPLIT) {
            gld16(Alo + aoff + k,           sAlo + ldsb);
            gld16(Alo + aoff + 16 * KD + k, sAlo + ldsb + 512);
            gld16(Blo + boff + k,           sBlo + ldsb);
            gld16(Blo + boff + 16 * KD + k, sBlo + ldsb + 512);
        }
        __syncthreads();

        bf16x8 ahi[4], alo[4];
#pragma unroll
        for (int mt = 0; mt < 4; mt++) {
            int r = wr * 64 + mt * 16 + i16;
            ahi[mt] = *(const bf16x8*)(sAhi + r * 32 + quad * 8);
            if constexpr (SPLIT) alo[mt] = *(const bf16x8*)(sAlo + r * 32 + quad * 8);
        }
#pragma unroll
        for (int nt = 0; nt < 4; nt++) {
            int r = wc * 64 + nt * 16 + i16;
            bf16x8 bhi = *(const bf16x8*)(sBhi + r * 32 + quad * 8);
            bf16x8 blo;
            if constexpr (SPLIT) blo = *(const bf16x8*)(sBlo + r * 32 + quad * 8);
#pragma unroll
            for (int mt = 0; mt < 4; mt++) {
                if constexpr (MODE == 3) {
                    acc[mt][nt] = __builtin_amdgcn_mfma_f32_16x16x32_f16(
                        __builtin_bit_cast(f16x8, ahi[mt]), __builtin_bit_cast(f16x8, bhi),
                        acc[mt][nt], 0, 0, 0);
                } else {
                    acc[mt][nt] = __builtin_amdgcn_mfma_f32_16x16x32_bf16(ahi[mt], bhi, acc[mt][nt], 0, 0, 0);
                    if constexpr (SPLIT) {
                        acc[mt][nt] = __builtin_amdgcn_mfma_f32_16x16x32_bf16(ahi[mt], blo, acc[mt][nt], 0, 0, 0);
                        acc[mt][nt] = __builtin_amdgcn_mfma_f32_16x16x32_bf16(alo[mt], bhi, acc[mt][nt], 0, 0, 0);
                    }
                }
            }
        }
    }

    // ---------------- epilogues ----------------
    if constexpr (MODE == 0) {
#pragma unroll
        for (int mt = 0; mt < 4; mt++)
#pragma unroll
            for (int nt = 0; nt < 4; nt++)
#pragma unroll
                for (int r = 0; r < 4; r++) {
                    int row = m0 + wr * 64 + mt * 16 + quad * 4 + r;
                    int col = n0 + wc * 64 + nt * 16 + i16;
                    float v = acc[mt][nt][r];
                    unsigned short h = f2bf(v);
                    Chi[(size_t)row * DM + col] = h;
                    Clo[(size_t)row * DM + col] = f2bf(v - bf2f(h));
                }
    } else if constexpr (MODE == 1) {
#pragma unroll
        for (int mt = 0; mt < 4; mt++)
#pragma unroll
            for (int nt = 0; nt < 4; nt++)
#pragma unroll
                for (int r = 0; r < 4; r++) {
                    int row = m0 + wr * 64 + mt * 16 + quad * 4 + r;
                    int col = n0 + wc * 64 + nt * 16 + i16;
                    Cf16[(size_t)row * DM + col] = (_Float16)acc[mt][nt][r];
                }
    } else {
#pragma unroll
        for (int mt = 0; mt < 4; mt++)
#pragma unroll
            for (int nt = 0; nt < 4; nt++)
#pragma unroll
                for (int r = 0; r < 4; r++) {
                    int row = m0 + wr * 64 + mt * 16 + quad * 4 + r;
                    int col = n0 + wc * 64 + nt * 16 + i16;
                    Cf32[(size_t)row * DM + col] = acc[mt][nt][r];
                }
    }
}

// ============ scores GEMM: 128x128 tile, 32x32x16 MFMA, split bf16 ============
// Grid (x = n-tile, y = m-tile). Wave quadrant 64x64 = 2x2 of 32x32 MFMAs.
// A-frag: A[m=lane&31][k=(lane>>5)*8+j]; C/D: col=lane&31, row=(reg&3)+8*(reg>>2)+4*(lane>>5).
// Epilogue: E = f16(exp(s - tile64max)), Tt = max, Zt = sumexp per (row, 64-col tile).
__global__ __launch_bounds__(256) void gemm32s(
    const unsigned short* __restrict__ A, const unsigned short* __restrict__ Alo,
    const unsigned short* __restrict__ B, const unsigned short* __restrict__ Blo,
    _Float16* __restrict__ Eo, float* __restrict__ Tt, float* __restrict__ Zt)
{
    __shared__ alignas(16) unsigned short sAhi[128 * 32];
    __shared__ alignas(16) unsigned short sBhi[128 * 32];
    __shared__ alignas(16) unsigned short sAlo[128 * 32];
    __shared__ alignas(16) unsigned short sBlo[128 * 32];

    const int m0 = blockIdx.y * 128, n0 = blockIdx.x * 128;
    const int t = threadIdx.x;
    const int wave = t >> 6, lane = t & 63;
    const int wr = wave >> 1, wc = wave & 1;
    const int l31 = lane & 31, q2 = lane >> 5;

    // staging identical to gemm128
    const int rs = wave * 32 + (lane >> 2);
    const int cs = (lane & 3) * 8;
    const size_t aoff = (size_t)(m0 + rs) * DM + cs;
    const size_t boff = (size_t)(n0 + rs) * DM + cs;
    const int ldsb = wave * 1024;

    f32x16 acc[2][2] = {};

    for (int k = 0; k < DM; k += 32) {
        __syncthreads();
        gld16(A + aoff + k,            sAhi + ldsb);
        gld16(A + aoff + 16 * DM + k,  sAhi + ldsb + 512);
        gld16(B + boff + k,            sBhi + ldsb);
        gld16(B + boff + 16 * DM + k,  sBhi + ldsb + 512);
        gld16(Alo + aoff + k,           sAlo + ldsb);
        gld16(Alo + aoff + 16 * DM + k, sAlo + ldsb + 512);
        gld16(Blo + boff + k,           sBlo + ldsb);
        gld16(Blo + boff + 16 * DM + k, sBlo + ldsb + 512);
        __syncthreads();

#pragma unroll
        for (int kk = 0; kk < 2; kk++) {
            bf16x8 ah[2], al[2], bh[2], bl[2];
#pragma unroll
            for (int mt = 0; mt < 2; mt++) {
                int off = (wr * 64 + mt * 32 + l31) * 32 + kk * 16 + q2 * 8;
                ah[mt] = *(const bf16x8*)(sAhi + off);
                al[mt] = *(const bf16x8*)(sAlo + off);
            }
#pragma unroll
            for (int nt = 0; nt < 2; nt++) {
                int off = (wc * 64 + nt * 32 + l31) * 32 + kk * 16 + q2 * 8;
                bh[nt] = *(const bf16x8*)(sBhi + off);
                bl[nt] = *(const bf16x8*)(sBlo + off);
            }
#pragma unroll
            for (int nt = 0; nt < 2; nt++)
#pragma unroll
                for (int mt = 0; mt < 2; mt++) {
                    acc[mt][nt] = __builtin_amdgcn_mfma_f32_32x32x16_bf16(ah[mt], bh[nt], acc[mt][nt], 0, 0, 0);
                    acc[mt][nt] = __builtin_amdgcn_mfma_f32_32x32x16_bf16(ah[mt], bl[nt], acc[mt][nt], 0, 0, 0);
                    acc[mt][nt] = __builtin_amdgcn_mfma_f32_32x32x16_bf16(al[mt], bh[nt], acc[mt][nt], 0, 0, 0);
                }
        }
    }

    const float scale = 0.03125f;  // 1/sqrt(1024)
    const int tix = (n0 + wc * 64) >> 6;
#pragma unroll
    for (int mt = 0; mt < 2; mt++)
#pragma unroll
        for (int reg = 0; reg < 16; reg++) {
            float s0 = acc[mt][0][reg] * scale;
            float s1 = acc[mt][1][reg] * scale;
            float mx = fmaxf(s0, s1);
            mx = fmaxf(mx, __shfl_xor(mx, 1));
            mx = fmaxf(mx, __shfl_xor(mx, 2));
            mx = fmaxf(mx, __shfl_xor(mx, 4));
            mx = fmaxf(mx, __shfl_xor(mx, 8));
            mx = fmaxf(mx, __shfl_xor(mx, 16));
            float e0 = __expf(s0 - mx), e1 = __expf(s1 - mx);
            float z = e0 + e1;
            z += __shfl_xor(z, 1);
            z += __shfl_xor(z, 2);
            z += __shfl_xor(z, 4);
            z += __shfl_xor(z, 8);
            z += __shfl_xor(z, 16);
            int row = m0 + wr * 64 + mt * 32 + (reg & 3) + 8 * (reg >> 2) + 4 * q2;
            if (l31 == 0) {
                Tt[(size_t)row * 128 + tix] = mx;
                Zt[(size_t)row * 128 + tix] = z;
            }
            size_t eb = (size_t)row * SEQ + n0 + wc * 64 + l31;
            Eo[eb +  0] = (_Float16)e0;
            Eo[eb + 32] = (_Float16)e1;
        }
}

// ---------------- transpose V [8192 x 1024] f16 -> Vt [1024 x 8192] ----------------
__global__ __launch_bounds__(256) void transpose_f16(const _Float16* __restrict__ in,
                                                     _Float16* __restrict__ out)
{
    __shared__ _Float16 tile[64][72];
    int bn = blockIdx.x * 64;
    int bm = blockIdx.y * 64;
    int t = threadIdx.x;
    int r = t >> 3, c = (t & 7) * 8;
#pragma unroll
    for (int p = 0; p < 2; p++) {
        int rr = p * 32 + r;
        H8 v; v.v = *(const int4*)(in + (size_t)(bm + rr) * DM + bn + c);
#pragma unroll
        for (int j = 0; j < 8; j++) tile[rr][c + j] = v.h[j];
    }
    __syncthreads();
#pragma unroll
    for (int p = 0; p < 2; p++) {
        int rr = p * 32 + r;
        H8 v;
#pragma unroll
        for (int j = 0; j < 8; j++) v.h[j] = tile[c + j][rr];
        *(int4*)(out + (size_t)(bn + rr) * SEQ + bm + c) = v.v;
    }
}

// ------- merged: per-row softmax scale from Tt/Zt, then in-place E *= scale -------
// one block per row; wave 0 reduces the 128 per-tile stats, LDS-broadcasts 128 scales
__global__ __launch_bounds__(256) void scale_rows(_Float16* __restrict__ E,
    const float* __restrict__ Tt, const float* __restrict__ Zt)
{
    __shared__ float sSc[128];
    int row = blockIdx.x;
    int t = threadIdx.x;
    if (t < 64) {
        size_t b = (size_t)row * 128 + t;
        float t0 = Tt[b], t1 = Tt[b + 64];
        float z0 = Zt[b], z1 = Zt[b + 64];
        float m = fmaxf(t0, t1);
        for (int sh = 1; sh < 64; sh <<= 1) m = fmaxf(m, __shfl_xor(m, sh));
        float l = z0 * __expf(t0 - m) + z1 * __expf(t1 - m);
        for (int sh = 1; sh < 64; sh <<= 1) l += __shfl_xor(l, sh);
        float inv = 1.0f / l;
        sSc[t]      = __expf(t0 - m) * inv;
        sSc[t + 64] = __expf(t1 - m) * inv;
    }
    __syncthreads();
    _Float16* pr = E + (size_t)row * SEQ;
#pragma unroll
    for (int p = 0; p < 4; p++) {
        int c = t * 8 + p * 2048;
        float sc = sSc[c >> 6];
        H8 v; v.v = *(const int4*)(pr + c);
        H8 o;
#pragma unroll
        for (int j = 0; j < 8; j++) o.h[j] = (_Float16)((float)v.h[j] * sc);
        *(int4*)(pr + c) = o.v;
    }
}

extern "C" void kernel_launch(void* const* d_in, const int* in_sizes, int n_in,
                              void* d_out, int out_size, void* d_ws, size_t ws_size,
                              hipStream_t stream)
{
    const float* x  = (const float*)d_in[0];
    const float* Wq = (const float*)d_in[1];
    const float* Wk = (const float*)d_in[2];
    const float* Wv = (const float*)d_in[3];
    float* Out = (float*)d_out;
    char* ws = (char*)d_ws;

    const size_t MB = 1024 * 1024;
    // Region [0, 128MB): first x-splits / W-splits / Vtmp, later E (after they are dead)
    unsigned short* xhi   = (unsigned short*)(ws + 0 * MB);
    unsigned short* xlo   = (unsigned short*)(ws + 16 * MB);
    unsigned short* Wqthi = (unsigned short*)(ws + 32 * MB);
    unsigned short* Wqtlo = (unsigned short*)(ws + 34 * MB);
    unsigned short* Wkthi = (unsigned short*)(ws + 36 * MB);
    unsigned short* Wktlo = (unsigned short*)(ws + 38 * MB);
    unsigned short* Wvthi = (unsigned short*)(ws + 40 * MB);
    unsigned short* Wvtlo = (unsigned short*)(ws + 42 * MB);
    _Float16*       Vtmp  = (_Float16*)     (ws + 44 * MB);   // dead after transpose
    _Float16*       E     = (_Float16*)     (ws + 0 * MB);    // 128 MB, written after splits dead

    size_t off = 128 * MB;
    unsigned short* Qhi = (unsigned short*)(ws + off); off += 16 * MB;
    unsigned short* Qlo = (unsigned short*)(ws + off); off += 16 * MB;
    unsigned short* Khi = (unsigned short*)(ws + off); off += 16 * MB;
    unsigned short* Klo = (unsigned short*)(ws + off); off += 16 * MB;
    _Float16*       Vt  = (_Float16*)      (ws + off); off += 16 * MB;
    float*          Tt  = (float*)         (ws + off); off += (size_t)SEQ * 128 * 4;
    float*          Zt  = (float*)         (ws + off); off += (size_t)SEQ * 128 * 4;

    // 1. split x
    split_x_kernel<<<(SEQ * DM) / (256 * 4), 256, 0, stream>>>(x, xhi, xlo, SEQ * DM);
    // 2. transpose+split all weights (one launch)
    wsplit3_kernel<<<dim3(16, 16, 3), 256, 0, stream>>>(Wq, Wk, Wv,
        Wqthi, Wqtlo, Wkthi, Wktlo, Wvthi, Wvtlo);
    // 3. Q and K projections (one launch; x=row-tile so XCD shares x-rows)
    gemm128<0, DM><<<dim3(SEQ / 128, DM / 128, 2), 256, 0, stream>>>(
        xhi, xlo, Wqthi, Wqtlo, Wkthi, Wktlo,
        Qhi, Qlo, Khi, Klo, nullptr, nullptr);
    // 4. V projection (row-major out)
    gemm128<1, DM><<<dim3(SEQ / 128, DM / 128), 256, 0, stream>>>(
        xhi, nullptr, Wvthi, nullptr, nullptr, nullptr,
        nullptr, nullptr, nullptr, nullptr, (_Float16*)Vtmp, nullptr);
    // 5. transpose V
    transpose_f16<<<dim3(DM / 64, SEQ / 64), 256, 0, stream>>>(Vtmp, Vt);
    // 6. scores (32x32x16 MFMA) -> E (exp rel 64-col tile max), Tt, Zt
    gemm32s<<<dim3(SEQ / 128, SEQ / 128), 256, 0, stream>>>(
        Qhi, Qlo, Khi, Klo, E, Tt, Zt);
    // 7. merged per-row scale reduce + in-place E scaling
    scale_rows<<<SEQ, 256, 0, stream>>>(E, Tt, Zt);
    // 8. O = P @ V; x=row-tile => the 8 d-tiles sharing an E-slice land on one XCD
    gemm128<3, SEQ><<<dim3(SEQ / 128, DM / 128), 256, 0, stream>>>(
        (const unsigned short*)E, nullptr, (const unsigned short*)Vt, nullptr, nullptr, nullptr,
        nullptr, nullptr, nullptr, nullptr, nullptr, Out);
}

// Round 9
// 887.302 us; speedup vs baseline: 1.0456x; 1.0456x over previous
//
#include <hip/hip_runtime.h>
#include <hip/hip_bf16.h>
#include <hip/hip_fp16.h>

#define SEQ 8192
#define DM  1024   // d_in == d_out == 1024

typedef __attribute__((ext_vector_type(8)))  short    bf16x8;
typedef __attribute__((ext_vector_type(8)))  _Float16 f16x8;
typedef __attribute__((ext_vector_type(4)))  float    f32x4;
typedef __attribute__((ext_vector_type(16))) float    f32x16;

union H8 { _Float16 h[8]; int4 v; };

__device__ __forceinline__ unsigned short f2bf(float f) {
    union { float f; unsigned u; } x; x.f = f;
    unsigned r = x.u + 0x7fffu + ((x.u >> 16) & 1u);
    return (unsigned short)(r >> 16);
}
__device__ __forceinline__ float bf2f(unsigned short h) {
    union { unsigned u; float f; } x; x.u = ((unsigned)h) << 16;
    return x.f;
}

// async global->LDS, 16B per lane; lds dest wave-uniform base (HW adds lane*16)
__device__ __forceinline__ void gld16(const unsigned short* g, unsigned short* l) {
    __builtin_amdgcn_global_load_lds(
        (const __attribute__((address_space(1))) void*)g,
        (__attribute__((address_space(3))) void*)l, 16, 0, 0);
}

// ---------------- split x (fp32 -> bf16 hi/lo) ----------------
__global__ __launch_bounds__(256) void split_x_kernel(const float* __restrict__ x,
    unsigned short* __restrict__ xhi, unsigned short* __restrict__ xlo, int n)
{
    int base = (blockIdx.x * 256 + threadIdx.x) * 4;
    if (base >= n) return;
    float4 v = *(const float4*)(x + base);
    float f[4] = {v.x, v.y, v.z, v.w};
    unsigned short h[4], l[4];
#pragma unroll
    for (int j = 0; j < 4; j++) { h[j] = f2bf(f[j]); l[j] = f2bf(f[j] - bf2f(h[j])); }
    ushort4 hv = {h[0], h[1], h[2], h[3]};
    ushort4 lv = {l[0], l[1], l[2], l[3]};
    *(ushort4*)(xhi + base) = hv;
    *(ushort4*)(xlo + base) = lv;
}

// --- transpose + split all 3 W [1024k x 1024n] -> Wt hi/lo [n][k]; blockIdx.z picks W ---
__global__ __launch_bounds__(256) void wsplit3_kernel(
    const float* W0, const float* W1, const float* W2,
    unsigned short* H0, unsigned short* L0,
    unsigned short* H1, unsigned short* L1,
    unsigned short* H2, unsigned short* L2)
{
    const float* W = (blockIdx.z == 0) ? W0 : (blockIdx.z == 1) ? W1 : W2;
    unsigned short* Wthi = (blockIdx.z == 0) ? H0 : (blockIdx.z == 1) ? H1 : H2;
    unsigned short* Wtlo = (blockIdx.z == 0) ? L0 : (blockIdx.z == 1) ? L1 : L2;

    __shared__ float tile[64][65];
    int bn = blockIdx.x * 64;
    int bk = blockIdx.y * 64;
    int t = threadIdx.x;
#pragma unroll
    for (int p = 0; p < 4; p++) {
        int r = p * 16 + (t >> 4);
        int c = (t & 15) * 4;
        float4 v = *(const float4*)(W + (size_t)(bk + r) * DM + bn + c);
        tile[r][c] = v.x; tile[r][c+1] = v.y; tile[r][c+2] = v.z; tile[r][c+3] = v.w;
    }
    __syncthreads();
#pragma unroll
    for (int p = 0; p < 2; p++) {
        int task = p * 256 + t;
        int rn = task >> 3;
        int kc = (task & 7) * 8;
        union { unsigned short u[8]; int4 v; } hh, ll;
#pragma unroll
        for (int j = 0; j < 8; j++) {
            float f = tile[kc + j][rn];
            hh.u[j] = f2bf(f);
            ll.u[j] = f2bf(f - bf2f(hh.u[j]));
        }
        size_t o = (size_t)(bn + rn) * DM + bk + kc;
        *(int4*)(Wthi + o) = hh.v;
        *(int4*)(Wtlo + o) = ll.v;
    }
}

// ============ 128x128-tile GEMM, 256 threads (4 waves, 64x64 each), BK=32 ============
// MODE 0: split bf16 -> split bf16 out; blockIdx.z picks (B,out) pair (Q/K projections)
// MODE 1: plain bf16 -> f16 out row-major (V projection), KD=1024
// MODE 3: plain f16 -> f32 out (PV), KD=8192; grid x=row-tile for XCD L2 sharing
template<int MODE, int KD>
__global__ __launch_bounds__(256) void gemm128(
    const unsigned short* A,   const unsigned short* Alo,
    const unsigned short* B_,  const unsigned short* Blo_,
    const unsigned short* B2,  const unsigned short* B2lo,
    unsigned short* Chi_, unsigned short* Clo_,
    unsigned short* Chi2, unsigned short* Clo2,
    _Float16* Cf16, float* Cf32)
{
    constexpr bool SPLIT = (MODE == 0);
    __shared__ alignas(16) unsigned short sAhi[128 * 32];
    __shared__ alignas(16) unsigned short sBhi[128 * 32];
    __shared__ alignas(16) unsigned short sAlo[SPLIT ? 128 * 32 : 16];
    __shared__ alignas(16) unsigned short sBlo[SPLIT ? 128 * 32 : 16];

    const unsigned short* B   = B_;
    const unsigned short* Blo = Blo_;
    unsigned short* Chi = Chi_;
    unsigned short* Clo = Clo_;
    if (MODE == 0 && blockIdx.z == 1) { B = B2; Blo = B2lo; Chi = Chi2; Clo = Clo2; }

    const int m0 = blockIdx.x * 128;
    const int n0 = blockIdx.y * 128;
    const int t = threadIdx.x;
    const int wave = t >> 6, lane = t & 63;
    const int wr = wave >> 1, wc = wave & 1;    // wave quadrant (64x64)
    const int i16 = lane & 15, quad = lane >> 4;

    // staging: wave stages rows wave*32 .. wave*32+31 (two 16-row chunks)
    const int rs = wave * 32 + (lane >> 2);
    const int cs = (lane & 3) * 8;
    const size_t aoff = (size_t)(m0 + rs) * KD + cs;
    const size_t boff = (size_t)(n0 + rs) * KD + cs;
    const int ldsb = wave * 1024;   // element offset of this wave's staging region

    f32x4 acc[4][4] = {};

    for (int k = 0; k < KD; k += 32) {
        __syncthreads();
        gld16(A + aoff + k,            sAhi + ldsb);
        gld16(A + aoff + 16 * KD + k,  sAhi + ldsb + 512);
        gld16(B + boff + k,            sBhi + ldsb);
        gld16(B + boff + 16 * KD + k,  sBhi + ldsb + 512);
        if constexpr (SPLIT) {
            gld16(Alo + aoff + k,           sAlo + ldsb);
            gld16(Alo + aoff + 16 * KD + k, sAlo + ldsb + 512);
            gld16(Blo + boff + k,           sBlo + ldsb);
            gld16(Blo + boff + 16 * KD + k, sBlo + ldsb + 512);
        }
        __syncthreads();

        bf16x8 ahi[4], alo[4];
#pragma unroll
        for (int mt = 0; mt < 4; mt++) {
            int r = wr * 64 + mt * 16 + i16;
            ahi[mt] = *(const bf16x8*)(sAhi + r * 32 + quad * 8);
            if constexpr (SPLIT) alo[mt] = *(const bf16x8*)(sAlo + r * 32 + quad * 8);
        }
#pragma unroll
        for (int nt = 0; nt < 4; nt++) {
            int r = wc * 64 + nt * 16 + i16;
            bf16x8 bhi = *(const bf16x8*)(sBhi + r * 32 + quad * 8);
            bf16x8 blo;
            if constexpr (SPLIT) blo = *(const bf16x8*)(sBlo + r * 32 + quad * 8);
#pragma unroll
            for (int mt = 0; mt < 4; mt++) {
                if constexpr (MODE == 3) {
                    acc[mt][nt] = __builtin_amdgcn_mfma_f32_16x16x32_f16(
                        __builtin_bit_cast(f16x8, ahi[mt]), __builtin_bit_cast(f16x8, bhi),
                        acc[mt][nt], 0, 0, 0);
                } else {
                    acc[mt][nt] = __builtin_amdgcn_mfma_f32_16x16x32_bf16(ahi[mt], bhi, acc[mt][nt], 0, 0, 0);
                    if constexpr (SPLIT) {
                        acc[mt][nt] = __builtin_amdgcn_mfma_f32_16x16x32_bf16(ahi[mt], blo, acc[mt][nt], 0, 0, 0);
                        acc[mt][nt] = __builtin_amdgcn_mfma_f32_16x16x32_bf16(alo[mt], bhi, acc[mt][nt], 0, 0, 0);
                    }
                }
            }
        }
    }

    // ---------------- epilogues ----------------
    if constexpr (MODE == 0) {
#pragma unroll
        for (int mt = 0; mt < 4; mt++)
#pragma unroll
            for (int nt = 0; nt < 4; nt++)
#pragma unroll
                for (int r = 0; r < 4; r++) {
                    int row = m0 + wr * 64 + mt * 16 + quad * 4 + r;
                    int col = n0 + wc * 64 + nt * 16 + i16;
                    float v = acc[mt][nt][r];
                    unsigned short h = f2bf(v);
                    Chi[(size_t)row * DM + col] = h;
                    Clo[(size_t)row * DM + col] = f2bf(v - bf2f(h));
                }
    } else if constexpr (MODE == 1) {
#pragma unroll
        for (int mt = 0; mt < 4; mt++)
#pragma unroll
            for (int nt = 0; nt < 4; nt++)
#pragma unroll
                for (int r = 0; r < 4; r++) {
                    int row = m0 + wr * 64 + mt * 16 + quad * 4 + r;
                    int col = n0 + wc * 64 + nt * 16 + i16;
                    Cf16[(size_t)row * DM + col] = (_Float16)acc[mt][nt][r];
                }
    } else {
#pragma unroll
        for (int mt = 0; mt < 4; mt++)
#pragma unroll
            for (int nt = 0; nt < 4; nt++)
#pragma unroll
                for (int r = 0; r < 4; r++) {
                    int row = m0 + wr * 64 + mt * 16 + quad * 4 + r;
                    int col = n0 + wc * 64 + nt * 16 + i16;
                    Cf32[(size_t)row * DM + col] = acc[mt][nt][r];
                }
    }
}

// ============ scores GEMM: 128x128 tile, 32x32x16 MFMA, split bf16 ============
// LDS layout: [kk-half][128 rows][16 cols]; each kk region = 128*16 = 2048 ELEMENTS
// (round-8 bug: used 4096 = total array size as the region stride -> OOB writes).
// Wave fragment read (l31,q2) -> kk*2048 + row*16 + q2*8 covers a contiguous 1 KB.
// A-frag: A[m=lane&31][k=(lane>>5)*8+j]; C/D: col=lane&31, row=(reg&3)+8*(reg>>2)+4*(lane>>5).
// Epilogue: E = f16(exp(s - tile64max)), Tt = max, Zt = sumexp per (row, 64-col tile).
__global__ __launch_bounds__(256) void gemm32s(
    const unsigned short* __restrict__ A, const unsigned short* __restrict__ Alo,
    const unsigned short* __restrict__ B, const unsigned short* __restrict__ Blo,
    _Float16* __restrict__ Eo, float* __restrict__ Tt, float* __restrict__ Zt)
{
    __shared__ alignas(16) unsigned short sAhi[2 * 128 * 16];
    __shared__ alignas(16) unsigned short sBhi[2 * 128 * 16];
    __shared__ alignas(16) unsigned short sAlo[2 * 128 * 16];
    __shared__ alignas(16) unsigned short sBlo[2 * 128 * 16];

    const int m0 = blockIdx.y * 128, n0 = blockIdx.x * 128;
    const int t = threadIdx.x;
    const int wave = t >> 6, lane = t & 63;
    const int wr = wave >> 1, wc = wave & 1;
    const int l31 = lane & 31, q2 = lane >> 5;

    // staging: wave w stages rows w*32..w*32+31; lane -> row w*32 + lane/2, col-half (lane&1)*8
    const int rs = wave * 32 + (lane >> 1);
    const int cs = (lane & 1) * 8;
    const size_t aoff = (size_t)(m0 + rs) * DM + cs;
    const size_t boff = (size_t)(n0 + rs) * DM + cs;
    const int ldsb = wave * 512;    // element offset within each kk region (2048 elems)

    f32x16 acc[2][2] = {};

    for (int k = 0; k < DM; k += 32) {
        __syncthreads();
        gld16(A + aoff + k,        sAhi + ldsb);           // kk=0 half (cols k..k+15)
        gld16(A + aoff + k + 16,   sAhi + 2048 + ldsb);    // kk=1 half (cols k+16..k+31)
        gld16(B + boff + k,        sBhi + ldsb);
        gld16(B + boff + k + 16,   sBhi + 2048 + ldsb);
        gld16(Alo + aoff + k,      sAlo + ldsb);
        gld16(Alo + aoff + k + 16, sAlo + 2048 + ldsb);
        gld16(Blo + boff + k,      sBlo + ldsb);
        gld16(Blo + boff + k + 16, sBlo + 2048 + ldsb);
        __syncthreads();

#pragma unroll
        for (int kk = 0; kk < 2; kk++) {
            bf16x8 ah[2], al[2], bh[2], bl[2];
#pragma unroll
            for (int mt = 0; mt < 2; mt++) {
                int off = kk * 2048 + (wr * 64 + mt * 32 + l31) * 16 + q2 * 8;
                ah[mt] = *(const bf16x8*)(sAhi + off);
                al[mt] = *(const bf16x8*)(sAlo + off);
            }
#pragma unroll
            for (int nt = 0; nt < 2; nt++) {
                int off = kk * 2048 + (wc * 64 + nt * 32 + l31) * 16 + q2 * 8;
                bh[nt] = *(const bf16x8*)(sBhi + off);
                bl[nt] = *(const bf16x8*)(sBlo + off);
            }
#pragma unroll
            for (int nt = 0; nt < 2; nt++)
#pragma unroll
                for (int mt = 0; mt < 2; mt++) {
                    acc[mt][nt] = __builtin_amdgcn_mfma_f32_32x32x16_bf16(ah[mt], bh[nt], acc[mt][nt], 0, 0, 0);
                    acc[mt][nt] = __builtin_amdgcn_mfma_f32_32x32x16_bf16(ah[mt], bl[nt], acc[mt][nt], 0, 0, 0);
                    acc[mt][nt] = __builtin_amdgcn_mfma_f32_32x32x16_bf16(al[mt], bh[nt], acc[mt][nt], 0, 0, 0);
                }
        }
    }

    const float scale = 0.03125f;  // 1/sqrt(1024)
    const int tix = (n0 + wc * 64) >> 6;
#pragma unroll
    for (int mt = 0; mt < 2; mt++)
#pragma unroll
        for (int reg = 0; reg < 16; reg++) {
            float s0 = acc[mt][0][reg] * scale;
            float s1 = acc[mt][1][reg] * scale;
            float mx = fmaxf(s0, s1);
            mx = fmaxf(mx, __shfl_xor(mx, 1));
            mx = fmaxf(mx, __shfl_xor(mx, 2));
            mx = fmaxf(mx, __shfl_xor(mx, 4));
            mx = fmaxf(mx, __shfl_xor(mx, 8));
            mx = fmaxf(mx, __shfl_xor(mx, 16));
            float e0 = __expf(s0 - mx), e1 = __expf(s1 - mx);
            float z = e0 + e1;
            z += __shfl_xor(z, 1);
            z += __shfl_xor(z, 2);
            z += __shfl_xor(z, 4);
            z += __shfl_xor(z, 8);
            z += __shfl_xor(z, 16);
            int row = m0 + wr * 64 + mt * 32 + (reg & 3) + 8 * (reg >> 2) + 4 * q2;
            if (l31 == 0) {
                Tt[(size_t)row * 128 + tix] = mx;
                Zt[(size_t)row * 128 + tix] = z;
            }
            size_t eb = (size_t)row * SEQ + n0 + wc * 64 + l31;
            Eo[eb +  0] = (_Float16)e0;
            Eo[eb + 32] = (_Float16)e1;
        }
}

// ---------------- transpose V [8192 x 1024] f16 -> Vt [1024 x 8192] ----------------
__global__ __launch_bounds__(256) void transpose_f16(const _Float16* __restrict__ in,
                                                     _Float16* __restrict__ out)
{
    __shared__ _Float16 tile[64][72];
    int bn = blockIdx.x * 64;
    int bm = blockIdx.y * 64;
    int t = threadIdx.x;
    int r = t >> 3, c = (t & 7) * 8;
#pragma unroll
    for (int p = 0; p < 2; p++) {
        int rr = p * 32 + r;
        H8 v; v.v = *(const int4*)(in + (size_t)(bm + rr) * DM + bn + c);
#pragma unroll
        for (int j = 0; j < 8; j++) tile[rr][c + j] = v.h[j];
    }
    __syncthreads();
#pragma unroll
    for (int p = 0; p < 2; p++) {
        int rr = p * 32 + r;
        H8 v;
#pragma unroll
        for (int j = 0; j < 8; j++) v.h[j] = tile[c + j][rr];
        *(int4*)(out + (size_t)(bn + rr) * SEQ + bm + c) = v.v;
    }
}

// ------- merged: per-row softmax scale from Tt/Zt, then in-place E *= scale -------
// one block per row; wave 0 reduces the 128 per-tile stats, LDS-broadcasts 128 scales
__global__ __launch_bounds__(256) void scale_rows(_Float16* __restrict__ E,
    const float* __restrict__ Tt, const float* __restrict__ Zt)
{
    __shared__ float sSc[128];
    int row = blockIdx.x;
    int t = threadIdx.x;
    if (t < 64) {
        size_t b = (size_t)row * 128 + t;
        float t0 = Tt[b], t1 = Tt[b + 64];
        float z0 = Zt[b], z1 = Zt[b + 64];
        float m = fmaxf(t0, t1);
        for (int sh = 1; sh < 64; sh <<= 1) m = fmaxf(m, __shfl_xor(m, sh));
        float l = z0 * __expf(t0 - m) + z1 * __expf(t1 - m);
        for (int sh = 1; sh < 64; sh <<= 1) l += __shfl_xor(l, sh);
        float inv = 1.0f / l;
        sSc[t]      = __expf(t0 - m) * inv;
        sSc[t + 64] = __expf(t1 - m) * inv;
    }
    __syncthreads();
    _Float16* pr = E + (size_t)row * SEQ;
#pragma unroll
    for (int p = 0; p < 4; p++) {
        int c = t * 8 + p * 2048;
        float sc = sSc[c >> 6];
        H8 v; v.v = *(const int4*)(pr + c);
        H8 o;
#pragma unroll
        for (int j = 0; j < 8; j++) o.h[j] = (_Float16)((float)v.h[j] * sc);
        *(int4*)(pr + c) = o.v;
    }
}

extern "C" void kernel_launch(void* const* d_in, const int* in_sizes, int n_in,
                              void* d_out, int out_size, void* d_ws, size_t ws_size,
                              hipStream_t stream)
{
    const float* x  = (const float*)d_in[0];
    const float* Wq = (const float*)d_in[1];
    const float* Wk = (const float*)d_in[2];
    const float* Wv = (const float*)d_in[3];
    float* Out = (float*)d_out;
    char* ws = (char*)d_ws;

    const size_t MB = 1024 * 1024;
    // Region [0, 128MB): first x-splits / W-splits / Vtmp, later E (after they are dead)
    unsigned short* xhi   = (unsigned short*)(ws + 0 * MB);
    unsigned short* xlo   = (unsigned short*)(ws + 16 * MB);
    unsigned short* Wqthi = (unsigned short*)(ws + 32 * MB);
    unsigned short* Wqtlo = (unsigned short*)(ws + 34 * MB);
    unsigned short* Wkthi = (unsigned short*)(ws + 36 * MB);
    unsigned short* Wktlo = (unsigned short*)(ws + 38 * MB);
    unsigned short* Wvthi = (unsigned short*)(ws + 40 * MB);
    unsigned short* Wvtlo = (unsigned short*)(ws + 42 * MB);
    _Float16*       Vtmp  = (_Float16*)     (ws + 44 * MB);   // dead after transpose
    _Float16*       E     = (_Float16*)     (ws + 0 * MB);    // 128 MB, written after splits dead

    size_t off = 128 * MB;
    unsigned short* Qhi = (unsigned short*)(ws + off); off += 16 * MB;
    unsigned short* Qlo = (unsigned short*)(ws + off); off += 16 * MB;
    unsigned short* Khi = (unsigned short*)(ws + off); off += 16 * MB;
    unsigned short* Klo = (unsigned short*)(ws + off); off += 16 * MB;
    _Float16*       Vt  = (_Float16*)      (ws + off); off += 16 * MB;
    float*          Tt  = (float*)         (ws + off); off += (size_t)SEQ * 128 * 4;
    float*          Zt  = (float*)         (ws + off); off += (size_t)SEQ * 128 * 4;

    // 1. split x
    split_x_kernel<<<(SEQ * DM) / (256 * 4), 256, 0, stream>>>(x, xhi, xlo, SEQ * DM);
    // 2. transpose+split all weights (one launch)
    wsplit3_kernel<<<dim3(16, 16, 3), 256, 0, stream>>>(Wq, Wk, Wv,
        Wqthi, Wqtlo, Wkthi, Wktlo, Wvthi, Wvtlo);
    // 3. Q and K projections (one launch; x=row-tile so XCD shares x-rows)
    gemm128<0, DM><<<dim3(SEQ / 128, DM / 128, 2), 256, 0, stream>>>(
        xhi, xlo, Wqthi, Wqtlo, Wkthi, Wktlo,
        Qhi, Qlo, Khi, Klo, nullptr, nullptr);
    // 4. V projection (row-major out)
    gemm128<1, DM><<<dim3(SEQ / 128, DM / 128), 256, 0, stream>>>(
        xhi, nullptr, Wvthi, nullptr, nullptr, nullptr,
        nullptr, nullptr, nullptr, nullptr, (_Float16*)Vtmp, nullptr);
    // 5. transpose V
    transpose_f16<<<dim3(DM / 64, SEQ / 64), 256, 0, stream>>>(Vtmp, Vt);
    // 6. scores (32x32x16 MFMA, conflict-free split-kk LDS layout) -> E, Tt, Zt
    gemm32s<<<dim3(SEQ / 128, SEQ / 128), 256, 0, stream>>>(
        Qhi, Qlo, Khi, Klo, E, Tt, Zt);
    // 7. merged per-row scale reduce + in-place E scaling
    scale_rows<<<SEQ, 256, 0, stream>>>(E, Tt, Zt);
    // 8. O = P @ V; x=row-tile => the 8 d-tiles sharing an E-slice land on one XCD
    gemm128<3, SEQ><<<dim3(SEQ / 128, DM / 128), 256, 0, stream>>>(
        (const unsigned short*)E, nullptr, (const unsigned short*)Vt, nullptr, nullptr, nullptr,
        nullptr, nullptr, nullptr, nullptr, nullptr, Out);
}

// Round 10
// 833.176 us; speedup vs baseline: 1.1136x; 1.0650x over previous
//
#include <hip/hip_runtime.h>
#include <hip/hip_bf16.h>
#include <hip/hip_fp16.h>

#define SEQ 8192
#define DM  1024   // d_in == d_out == 1024

typedef __attribute__((ext_vector_type(8))) short    bf16x8;
typedef __attribute__((ext_vector_type(8))) _Float16 f16x8;
typedef __attribute__((ext_vector_type(4))) float    f32x4;

union H8 { _Float16 h[8]; int4 v; };

__device__ __forceinline__ unsigned short f2bf(float f) {
    union { float f; unsigned u; } x; x.f = f;
    unsigned r = x.u + 0x7fffu + ((x.u >> 16) & 1u);
    return (unsigned short)(r >> 16);
}
__device__ __forceinline__ float bf2f(unsigned short h) {
    union { unsigned u; float f; } x; x.u = ((unsigned)h) << 16;
    return x.f;
}

// async global->LDS, 16B per lane; lds dest wave-uniform base (HW adds lane*16)
__device__ __forceinline__ void gld16(const unsigned short* g, unsigned short* l) {
    __builtin_amdgcn_global_load_lds(
        (const __attribute__((address_space(1))) void*)g,
        (__attribute__((address_space(3))) void*)l, 16, 0, 0);
}

// ------- merged prep: blocks [0,8192) split x; blocks [8192,8960) transpose+split W -------
__global__ __launch_bounds__(256) void prep_kernel(const float* __restrict__ x,
    unsigned short* __restrict__ xhi, unsigned short* __restrict__ xlo,
    const float* W0, const float* W1, const float* W2,
    unsigned short* H0, unsigned short* L0,
    unsigned short* H1, unsigned short* L1,
    unsigned short* H2, unsigned short* L2)
{
    __shared__ float tile[64][65];
    int t = threadIdx.x;

    if (blockIdx.x < 8192) {
        // ---- split x (fp32 -> bf16 hi/lo), 1024 elems per block ----
        int base = (blockIdx.x * 256 + t) * 4;
        float4 v = *(const float4*)(x + base);
        float f[4] = {v.x, v.y, v.z, v.w};
        unsigned short h[4], l[4];
#pragma unroll
        for (int j = 0; j < 4; j++) { h[j] = f2bf(f[j]); l[j] = f2bf(f[j] - bf2f(h[j])); }
        ushort4 hv = {h[0], h[1], h[2], h[3]};
        ushort4 lv = {l[0], l[1], l[2], l[3]};
        *(ushort4*)(xhi + base) = hv;
        *(ushort4*)(xlo + base) = lv;
        return;
    }

    // ---- transpose + split W [1024k x 1024n] -> Wt hi/lo [n][k] ----
    int id = blockIdx.x - 8192;          // 0..767
    int z  = id >> 8;                    // which W
    int rem = id & 255;
    int bn = (rem & 15) * 64;
    int bk = (rem >> 4) * 64;
    const float* W = (z == 0) ? W0 : (z == 1) ? W1 : W2;
    unsigned short* Wthi = (z == 0) ? H0 : (z == 1) ? H1 : H2;
    unsigned short* Wtlo = (z == 0) ? L0 : (z == 1) ? L1 : L2;

#pragma unroll
    for (int p = 0; p < 4; p++) {
        int r = p * 16 + (t >> 4);
        int c = (t & 15) * 4;
        float4 v = *(const float4*)(W + (size_t)(bk + r) * DM + bn + c);
        tile[r][c] = v.x; tile[r][c+1] = v.y; tile[r][c+2] = v.z; tile[r][c+3] = v.w;
    }
    __syncthreads();
#pragma unroll
    for (int p = 0; p < 2; p++) {
        int task = p * 256 + t;
        int rn = task >> 3;
        int kc = (task & 7) * 8;
        union { unsigned short u[8]; int4 v; } hh, ll;
#pragma unroll
        for (int j = 0; j < 8; j++) {
            float f = tile[kc + j][rn];
            hh.u[j] = f2bf(f);
            ll.u[j] = f2bf(f - bf2f(hh.u[j]));
        }
        size_t o = (size_t)(bn + rn) * DM + bk + kc;
        *(int4*)(Wthi + o) = hh.v;
        *(int4*)(Wtlo + o) = ll.v;
    }
}

// ============ 128x128-tile GEMM, 256 threads (4 waves, 64x64 each), BK=32 ============
// A:[M x KD], B:[N x KD] row-major (contraction contiguous), ushort elements.
// Grid mapping: MODE 2 uses (x=n-tile, y=m-tile); all others use (x=m-tile, y=n-tile)
// so that XCD = flat_id%8 = row-tile%8 -> the d-tiles sharing an A-slice co-reside
// on one XCD and share its L2 (cuts E re-reads from L3 ~4x in PV).
// MODE 0: split bf16 -> split bf16 out; blockIdx.z=0 -> (B_,Blo_,Chi_,Clo_), z=1 -> (B2,...)
// MODE 1: plain bf16 -> f16 out row-major (V projection), KD=1024
// MODE 2: split bf16 -> scores epilogue: E=f16(exp(s-max64)), T=max, Z=sumexp, KD=1024
// MODE 3: plain f16 -> f32 out (PV), KD=8192
template<int MODE, int KD>
__global__ __launch_bounds__(256) void gemm128(
    const unsigned short* A,   const unsigned short* Alo,
    const unsigned short* B_,  const unsigned short* Blo_,
    const unsigned short* B2,  const unsigned short* B2lo,
    unsigned short* Chi_, unsigned short* Clo_,
    unsigned short* Chi2, unsigned short* Clo2,
    _Float16* Cf16, float* Cf32,
    _Float16* Eo, float* Tt, float* Zt)
{
    constexpr bool SPLIT = (MODE == 0 || MODE == 2);
    __shared__ alignas(16) unsigned short sAhi[128 * 32];
    __shared__ alignas(16) unsigned short sBhi[128 * 32];
    __shared__ alignas(16) unsigned short sAlo[SPLIT ? 128 * 32 : 16];
    __shared__ alignas(16) unsigned short sBlo[SPLIT ? 128 * 32 : 16];

    const unsigned short* B   = B_;
    const unsigned short* Blo = Blo_;
    unsigned short* Chi = Chi_;
    unsigned short* Clo = Clo_;
    if (MODE == 0 && blockIdx.z == 1) { B = B2; Blo = B2lo; Chi = Chi2; Clo = Clo2; }

    const int m0 = (MODE == 2 ? blockIdx.y : blockIdx.x) * 128;
    const int n0 = (MODE == 2 ? blockIdx.x : blockIdx.y) * 128;
    const int t = threadIdx.x;
    const int wave = t >> 6, lane = t & 63;
    const int wr = wave >> 1, wc = wave & 1;    // wave quadrant (64x64)
    const int i16 = lane & 15, quad = lane >> 4;

    // staging: wave stages rows wave*32 .. wave*32+31 (two 16-row chunks)
    const int rs = wave * 32 + (lane >> 2);
    const int cs = (lane & 3) * 8;
    const size_t aoff = (size_t)(m0 + rs) * KD + cs;
    const size_t boff = (size_t)(n0 + rs) * KD + cs;
    const int ldsb = wave * 1024;   // element offset of this wave's staging region

    f32x4 acc[4][4] = {};

    for (int k = 0; k < KD; k += 32) {
        __syncthreads();
        gld16(A + aoff + k,            sAhi + ldsb);
        gld16(A + aoff + 16 * KD + k,  sAhi + ldsb + 512);
        gld16(B + boff + k,            sBhi + ldsb);
        gld16(B + boff + 16 * KD + k,  sBhi + ldsb + 512);
        if constexpr (SPLIT) {
            gld16(Alo + aoff + k,           sAlo + ldsb);
            gld16(Alo + aoff + 16 * KD + k, sAlo + ldsb + 512);
            gld16(Blo + boff + k,           sBlo + ldsb);
            gld16(Blo + boff + 16 * KD + k, sBlo + ldsb + 512);
        }
        __syncthreads();

        bf16x8 ahi[4], alo[4];
#pragma unroll
        for (int mt = 0; mt < 4; mt++) {
            int r = wr * 64 + mt * 16 + i16;
            ahi[mt] = *(const bf16x8*)(sAhi + r * 32 + quad * 8);
            if constexpr (SPLIT) alo[mt] = *(const bf16x8*)(sAlo + r * 32 + quad * 8);
        }
#pragma unroll
        for (int nt = 0; nt < 4; nt++) {
            int r = wc * 64 + nt * 16 + i16;
            bf16x8 bhi = *(const bf16x8*)(sBhi + r * 32 + quad * 8);
            bf16x8 blo;
            if constexpr (SPLIT) blo = *(const bf16x8*)(sBlo + r * 32 + quad * 8);
#pragma unroll
            for (int mt = 0; mt < 4; mt++) {
                if constexpr (MODE == 3) {
                    acc[mt][nt] = __builtin_amdgcn_mfma_f32_16x16x32_f16(
                        __builtin_bit_cast(f16x8, ahi[mt]), __builtin_bit_cast(f16x8, bhi),
                        acc[mt][nt], 0, 0, 0);
                } else {
                    acc[mt][nt] = __builtin_amdgcn_mfma_f32_16x16x32_bf16(ahi[mt], bhi, acc[mt][nt], 0, 0, 0);
                    if constexpr (SPLIT) {
                        acc[mt][nt] = __builtin_amdgcn_mfma_f32_16x16x32_bf16(ahi[mt], blo, acc[mt][nt], 0, 0, 0);
                        acc[mt][nt] = __builtin_amdgcn_mfma_f32_16x16x32_bf16(alo[mt], bhi, acc[mt][nt], 0, 0, 0);
                    }
                }
            }
        }
    }

    // ---------------- epilogues ----------------
    if constexpr (MODE == 0) {
#pragma unroll
        for (int mt = 0; mt < 4; mt++)
#pragma unroll
            for (int nt = 0; nt < 4; nt++)
#pragma unroll
                for (int r = 0; r < 4; r++) {
                    int row = m0 + wr * 64 + mt * 16 + quad * 4 + r;
                    int col = n0 + wc * 64 + nt * 16 + i16;
                    float v = acc[mt][nt][r];
                    unsigned short h = f2bf(v);
                    Chi[(size_t)row * DM + col] = h;
                    Clo[(size_t)row * DM + col] = f2bf(v - bf2f(h));
                }
    } else if constexpr (MODE == 1) {
#pragma unroll
        for (int mt = 0; mt < 4; mt++)
#pragma unroll
            for (int nt = 0; nt < 4; nt++)
#pragma unroll
                for (int r = 0; r < 4; r++) {
                    int row = m0 + wr * 64 + mt * 16 + quad * 4 + r;
                    int col = n0 + wc * 64 + nt * 16 + i16;
                    Cf16[(size_t)row * DM + col] = (_Float16)acc[mt][nt][r];
                }
    } else if constexpr (MODE == 3) {
#pragma unroll
        for (int mt = 0; mt < 4; mt++)
#pragma unroll
            for (int nt = 0; nt < 4; nt++)
#pragma unroll
                for (int r = 0; r < 4; r++) {
                    int row = m0 + wr * 64 + mt * 16 + quad * 4 + r;
                    int col = n0 + wc * 64 + nt * 16 + i16;
                    Cf32[(size_t)row * DM + col] = acc[mt][nt][r];
                }
    } else {  // MODE 2: scores -> E = exp(s - tile64max), T (max), Z (sumexp), per 64-col tile
        const float scale = 0.03125f;  // 1/sqrt(1024)
        const int tix = (n0 + wc * 64) >> 6;   // 64-col tile index, 128 per row
#pragma unroll
        for (int mt = 0; mt < 4; mt++)
#pragma unroll
            for (int r = 0; r < 4; r++) {
                float s0 = acc[mt][0][r] * scale, s1 = acc[mt][1][r] * scale;
                float s2 = acc[mt][2][r] * scale, s3 = acc[mt][3][r] * scale;
                float mx = fmaxf(fmaxf(s0, s1), fmaxf(s2, s3));
                mx = fmaxf(mx, __shfl_xor(mx, 1));
                mx = fmaxf(mx, __shfl_xor(mx, 2));
                mx = fmaxf(mx, __shfl_xor(mx, 4));
                mx = fmaxf(mx, __shfl_xor(mx, 8));
                float e0 = __expf(s0 - mx), e1 = __expf(s1 - mx);
                float e2 = __expf(s2 - mx), e3 = __expf(s3 - mx);
                float z = e0 + e1 + e2 + e3;
                z += __shfl_xor(z, 1);
                z += __shfl_xor(z, 2);
                z += __shfl_xor(z, 4);
                z += __shfl_xor(z, 8);
                int row = m0 + wr * 64 + mt * 16 + quad * 4 + r;
                if (i16 == 0) {
                    Tt[(size_t)row * 128 + tix] = mx;
                    Zt[(size_t)row * 128 + tix] = z;
                }
                size_t eb = (size_t)row * SEQ + n0 + wc * 64 + i16;
                Eo[eb +  0] = (_Float16)e0;
                Eo[eb + 16] = (_Float16)e1;
                Eo[eb + 32] = (_Float16)e2;
                Eo[eb + 48] = (_Float16)e3;
            }
    }
}

// ---------------- transpose V [8192 x 1024] f16 -> Vt [1024 x 8192] ----------------
__global__ __launch_bounds__(256) void transpose_f16(const _Float16* __restrict__ in,
                                                     _Float16* __restrict__ out)
{
    __shared__ _Float16 tile[64][72];
    int bn = blockIdx.x * 64;
    int bm = blockIdx.y * 64;
    int t = threadIdx.x;
    int r = t >> 3, c = (t & 7) * 8;
#pragma unroll
    for (int p = 0; p < 2; p++) {
        int rr = p * 32 + r;
        H8 v; v.v = *(const int4*)(in + (size_t)(bm + rr) * DM + bn + c);
#pragma unroll
        for (int j = 0; j < 8; j++) tile[rr][c + j] = v.h[j];
    }
    __syncthreads();
#pragma unroll
    for (int p = 0; p < 2; p++) {
        int rr = p * 32 + r;
        H8 v;
#pragma unroll
        for (int j = 0; j < 8; j++) v.h[j] = tile[c + j][rr];
        *(int4*)(out + (size_t)(bn + rr) * SEQ + bm + c) = v.v;
    }
}

// ------- per-row softmax scale from per-tile stats: Sc[r][t] = e^{T-m}/l -------
// one wave per row, 2 tiles per lane (128 tiles of 64 cols)
__global__ __launch_bounds__(256) void sc_reduce(const float* __restrict__ Tt,
    const float* __restrict__ Zt, float* __restrict__ Sc)
{
    int row = blockIdx.x * 4 + (threadIdx.x >> 6);
    int lane = threadIdx.x & 63;
    size_t b = (size_t)row * 128 + lane;
    float t0 = Tt[b], t1 = Tt[b + 64];
    float z0 = Zt[b], z1 = Zt[b + 64];
    float m = fmaxf(t0, t1);
    for (int sh = 1; sh < 64; sh <<= 1) m = fmaxf(m, __shfl_xor(m, sh));
    float l = z0 * __expf(t0 - m) + z1 * __expf(t1 - m);
    for (int sh = 1; sh < 64; sh <<= 1) l += __shfl_xor(l, sh);
    float inv = 1.0f / l;
    Sc[b]      = __expf(t0 - m) * inv;
    Sc[b + 64] = __expf(t1 - m) * inv;
}

// ------- in-place E *= Sc[row][col>>6]  (memory-bound, 256 MB r/w) -------
__global__ __launch_bounds__(256) void e_scale(_Float16* __restrict__ E,
                                               const float* __restrict__ Sc)
{
    int row = blockIdx.x;
    _Float16* pr = E + (size_t)row * SEQ;
    const float* ps = Sc + (size_t)row * 128;
#pragma unroll
    for (int p = 0; p < 4; p++) {
        int c = threadIdx.x * 8 + p * 2048;
        float sc = ps[c >> 6];
        H8 v; v.v = *(const int4*)(pr + c);
        H8 o;
#pragma unroll
        for (int j = 0; j < 8; j++) o.h[j] = (_Float16)((float)v.h[j] * sc);
        *(int4*)(pr + c) = o.v;
    }
}

extern "C" void kernel_launch(void* const* d_in, const int* in_sizes, int n_in,
                              void* d_out, int out_size, void* d_ws, size_t ws_size,
                              hipStream_t stream)
{
    const float* x  = (const float*)d_in[0];
    const float* Wq = (const float*)d_in[1];
    const float* Wk = (const float*)d_in[2];
    const float* Wv = (const float*)d_in[3];
    float* Out = (float*)d_out;
    char* ws = (char*)d_ws;

    const size_t MB = 1024 * 1024;
    // Region [0, 128MB): first x-splits / W-splits / Vtmp, later E (after they are dead)
    unsigned short* xhi   = (unsigned short*)(ws + 0 * MB);
    unsigned short* xlo   = (unsigned short*)(ws + 16 * MB);
    unsigned short* Wqthi = (unsigned short*)(ws + 32 * MB);
    unsigned short* Wqtlo = (unsigned short*)(ws + 34 * MB);
    unsigned short* Wkthi = (unsigned short*)(ws + 36 * MB);
    unsigned short* Wktlo = (unsigned short*)(ws + 38 * MB);
    unsigned short* Wvthi = (unsigned short*)(ws + 40 * MB);
    unsigned short* Wvtlo = (unsigned short*)(ws + 42 * MB);
    _Float16*       Vtmp  = (_Float16*)     (ws + 44 * MB);   // dead after transpose
    _Float16*       E     = (_Float16*)     (ws + 0 * MB);    // 128 MB, written after splits dead

    size_t off = 128 * MB;
    unsigned short* Qhi = (unsigned short*)(ws + off); off += 16 * MB;
    unsigned short* Qlo = (unsigned short*)(ws + off); off += 16 * MB;
    unsigned short* Khi = (unsigned short*)(ws + off); off += 16 * MB;
    unsigned short* Klo = (unsigned short*)(ws + off); off += 16 * MB;
    _Float16*       Vt  = (_Float16*)      (ws + off); off += 16 * MB;
    float*          Tt  = (float*)         (ws + off); off += (size_t)SEQ * 128 * 4;
    float*          Zt  = (float*)         (ws + off); off += (size_t)SEQ * 128 * 4;
    float*          Sc  = (float*)         (ws + off); off += (size_t)SEQ * 128 * 4;

    // 1. split x + transpose/split all 3 weights, one launch
    prep_kernel<<<8192 + 768, 256, 0, stream>>>(x, xhi, xlo, Wq, Wk, Wv,
        Wqthi, Wqtlo, Wkthi, Wktlo, Wvthi, Wvtlo);
    // 2. Q and K projections (one launch; x=row-tile so XCD shares x-rows)
    gemm128<0, DM><<<dim3(SEQ / 128, DM / 128, 2), 256, 0, stream>>>(
        xhi, xlo, Wqthi, Wqtlo, Wkthi, Wktlo,
        Qhi, Qlo, Khi, Klo, nullptr, nullptr, nullptr, nullptr, nullptr);
    // 3. V projection (row-major out)
    gemm128<1, DM><<<dim3(SEQ / 128, DM / 128), 256, 0, stream>>>(
        xhi, nullptr, Wvthi, nullptr, nullptr, nullptr,
        nullptr, nullptr, nullptr, nullptr, (_Float16*)Vtmp, nullptr, nullptr, nullptr, nullptr);
    // 4. transpose V
    transpose_f16<<<dim3(DM / 64, SEQ / 64), 256, 0, stream>>>(Vtmp, Vt);
    // 5. scores -> E (exp rel 64-col tile max), Tt, Zt
    gemm128<2, DM><<<dim3(SEQ / 128, SEQ / 128), 256, 0, stream>>>(
        Qhi, Qlo, Khi, Klo, nullptr, nullptr,
        nullptr, nullptr, nullptr, nullptr, nullptr, nullptr, E, Tt, Zt);
    // 6. per-row/tile softmax scale (reads only 8 MB of stats)
    sc_reduce<<<SEQ / 4, 256, 0, stream>>>(Tt, Zt, Sc);
    // 7. E -> P in place (single memory-bound pass)
    e_scale<<<SEQ, 256, 0, stream>>>(E, Sc);
    // 8. O = P @ V; x=row-tile => the 8 d-tiles sharing an E-slice land on one XCD
    gemm128<3, SEQ><<<dim3(SEQ / 128, DM / 128), 256, 0, stream>>>(
        (const unsigned short*)E, nullptr, (const unsigned short*)Vt, nullptr, nullptr, nullptr,
        nullptr, nullptr, nullptr, nullptr, nullptr, Out, nullptr, nullptr, nullptr);
}